// Round 3
// baseline (84.009 us; speedup 1.0000x reference)
//
#include <hip/hip_runtime.h>
#include <stdint.h>

typedef unsigned long long u64;

// Binarized MLP: every matmul is sign(x) @ sign(w)^T => XOR+popcount on
// bit-packed rows: dot = K - 2*popcount(xa ^ xw). Layers 1-3 only feed the
// next binarize, so only sign bits propagate (packed via __ballot, wave=64).
// Round 2: C=2 columns/thread (halves LDS instrs), b128 LDS reads, x-pack
// inlined into the fused kernel, weight packs merged into one dispatch.

#define NB   16384   // batch
#define DIN  784     // input dim
#define HID  512     // hidden dim
#define DOUT 10      // output dim
#define KW1  13      // ceil(784/64)
#define KW2  8       // 512/64
#define RB   32      // batch rows per block
#define THR  256     // threads per fused block (4 waves), 2 columns/thread
#define PSTR 14      // padded row stride for layer-1 acts (112B, 16B-aligned)

// ---------------- combined weight pack (one dispatch) ----------------
// Pack sign bits of each weight matrix. w1/w2/w3 transposed-packed
// WT[k*HID + r] for lane-coalesced per-column loads; w4 row-packed.
// Pad bits (K=784 tail) = 0 on both operands -> never mismatch.
__global__ void bmlp_pack_w(const float* __restrict__ w1, const float* __restrict__ w2,
                            const float* __restrict__ w3, const float* __restrict__ w4,
                            u64* __restrict__ W1T, u64* __restrict__ W2T,
                            u64* __restrict__ W3T, u64* __restrict__ W4p)
{
    int gw   = (int)((blockIdx.x * blockDim.x + threadIdx.x) >> 6);
    int lane = threadIdx.x & 63;

    if (gw < HID * KW1) {                       // w1: [512][784] -> W1T[13][512]
        int r = gw / KW1, k = gw - r * KW1;
        int e = k * 64 + lane;
        float v = (e < DIN) ? w1[r * DIN + e] : 1.0f;   // pad -> bit 0
        u64 word = __ballot(v < 0.0f);
        if (lane == 0) W1T[k * HID + r] = word;
        return;
    }
    gw -= HID * KW1;
    if (gw < HID * KW2) {                       // w2: [512][512] -> W2T[8][512]
        int r = gw >> 3, k = gw & 7;
        float v = w2[r * HID + k * 64 + lane];
        u64 word = __ballot(v < 0.0f);
        if (lane == 0) W2T[k * HID + r] = word;
        return;
    }
    gw -= HID * KW2;
    if (gw < HID * KW2) {                       // w3
        int r = gw >> 3, k = gw & 7;
        float v = w3[r * HID + k * 64 + lane];
        u64 word = __ballot(v < 0.0f);
        if (lane == 0) W3T[k * HID + r] = word;
        return;
    }
    gw -= HID * KW2;
    if (gw < DOUT * KW2) {                      // w4: [10][512] -> W4p[10][8]
        int r = gw >> 3, k = gw & 7;
        float v = w4[r * HID + k * 64 + lane];
        u64 word = __ballot(v < 0.0f);
        if (lane == 0) W4p[r * KW2 + k] = word;
    }
}

// BN+hardtanh sign epilogue, reference op order (hardtanh preserves sign):
// y = ((dot + b) - m) * A + be, A = g * (1/sqrt(v+eps)); IEEE rn, no fusion.
__device__ __forceinline__ float bn_y(int dot, float b, float m, float A, float be)
{
    float xl = __fadd_rn((float)dot, b);        // dot is an exact small integer
    return __fadd_rn(__fmul_rn(__fsub_rn(xl, m), A), be);
}

// One binarized layer. 256 threads; thread t computes output columns t and
// t+256. All LDS row reads are wave-broadcast (conflict-free), b128-wide.
// Wave w ballots output words w (col block t) and 4+w (col block t+256).
template<int KW, int STRIDE>
__device__ __forceinline__ void bin_layer(const u64* in, u64* outw,
    const u64* __restrict__ WT,
    const float* __restrict__ b, const float* __restrict__ g,
    const float* __restrict__ be, const float* __restrict__ m,
    const float* __restrict__ v, float eps, int K)
{
    const int t = threadIdx.x, w = t >> 6, lane = t & 63;
    const int j1 = t + THR;

    u64 wr0[KW], wr1[KW];
#pragma unroll
    for (int k = 0; k < KW; ++k) {              // lane-coalesced u64 loads
        wr0[k] = WT[k * HID + t];
        wr1[k] = WT[k * HID + j1];
    }
    const float b0 = b[t],  b1v = b[j1];
    const float m0 = m[t],  m1v = m[j1];
    const float e0 = be[t], e1v = be[j1];
    const float A0 = __fmul_rn(g[t],  __fdiv_rn(1.0f, __fsqrt_rn(__fadd_rn(v[t],  eps))));
    const float A1 = __fmul_rn(g[j1], __fdiv_rn(1.0f, __fsqrt_rn(__fadd_rn(v[j1], eps))));

#pragma unroll 4
    for (int r = 0; r < RB; ++r) {
        const u64* row = in + r * STRIDE;
        const ulonglong2* row2 = reinterpret_cast<const ulonglong2*>(row);
        int p0a = 0, p0b = 0, p1a = 0, p1b = 0;
#pragma unroll
        for (int kk = 0; kk < KW / 2; ++kk) {   // b128 broadcast reads
            ulonglong2 a = row2[kk];
            p0a += __popcll(a.x ^ wr0[2 * kk]);
            p0b += __popcll(a.y ^ wr0[2 * kk + 1]);
            p1a += __popcll(a.x ^ wr1[2 * kk]);
            p1b += __popcll(a.y ^ wr1[2 * kk + 1]);
        }
        if (KW & 1) {                           // layer-1 tail word 12
            u64 a = row[KW - 1];
            p0a += __popcll(a ^ wr0[KW - 1]);
            p1a += __popcll(a ^ wr1[KW - 1]);
        }
        float y0 = bn_y(K - 2 * (p0a + p0b), b0,  m0,  A0, e0);
        float y1 = bn_y(K - 2 * (p1a + p1b), b1v, m1v, A1, e1v);
        u64 bal0 = __ballot(y0 < 0.0f);         // bit=1 <=> -1
        u64 bal1 = __ballot(y1 < 0.0f);
        if (lane == 0) {
            outw[r * KW2 + w]     = bal0;
            outw[r * KW2 + 4 + w] = bal1;
        }
    }
}

__global__ __launch_bounds__(THR)
void bmlp_fused(const float* __restrict__ x,
                const u64* __restrict__ W1T, const u64* __restrict__ W2T,
                const u64* __restrict__ W3T, const u64* __restrict__ W4p,
                const float* __restrict__ b1, const float* __restrict__ g1,
                const float* __restrict__ be1, const float* __restrict__ m1,
                const float* __restrict__ v1,
                const float* __restrict__ b2, const float* __restrict__ g2,
                const float* __restrict__ be2, const float* __restrict__ m2,
                const float* __restrict__ v2,
                const float* __restrict__ b3, const float* __restrict__ g3,
                const float* __restrict__ be3, const float* __restrict__ m3,
                const float* __restrict__ v3,
                const float* __restrict__ b4,
                float* __restrict__ out)
{
    __shared__ __align__(16) u64 P[RB * PSTR];  // layer-1 acts; reused (stride 8) for layer-2 out
    __shared__ __align__(16) u64 Q[RB * KW2];   // layer-1 / layer-3 out
    const int t = threadIdx.x, w = t >> 6, lane = t & 63;
    const int row0 = blockIdx.x * RB;

    // inline x-pack: wave w packs rows [w*8, w*8+8), ballot straight to LDS
    {
        const float* xb = x + (size_t)(row0 + w * 8) * DIN;
#pragma unroll 2
        for (int r = 0; r < 8; ++r) {
#pragma unroll
            for (int k = 0; k < KW1; ++k) {
                int e = k * 64 + lane;
                float v = (e < DIN) ? xb[(size_t)r * DIN + e] : 1.0f;  // pad -> bit 0
                u64 word = __ballot(v < 0.0f);
                if (lane == 0) P[(w * 8 + r) * PSTR + k] = word;
            }
        }
    }
    __syncthreads();

    bin_layer<KW1, PSTR>(P, Q, W1T, b1, g1, be1, m1, v1, 1e-5f, DIN);
    __syncthreads();
    bin_layer<KW2, KW2>(Q, P, W2T, b2, g2, be2, m2, v2, 1e-5f, HID);   // P reused, stride 8
    __syncthreads();
    bin_layer<KW2, KW2>(P, Q, W3T, b3, g3, be3, m3, v3, 512.0f, HID);  // EPS3 source bug: 512
    __syncthreads();

    // layer 4: out = dot + b4 (fp32). 320 tasks, two passes.
    {
        int r = t >> 3, jj = t & 7;             // pass 1: cols 0..7, all 32 rows
        const u64* row = Q + r * KW2;
        int mm = 0;
#pragma unroll
        for (int k = 0; k < KW2; ++k)
            mm += __popcll(row[k] ^ W4p[jj * KW2 + k]);
        out[(size_t)(row0 + r) * DOUT + jj] = __fadd_rn((float)(HID - 2 * mm), b4[jj]);
    }
    if (t < 64) {                               // pass 2: cols 8..9
        int r = t >> 1, jj = 8 + (t & 1);
        const u64* row = Q + r * KW2;
        int mm = 0;
#pragma unroll
        for (int k = 0; k < KW2; ++k)
            mm += __popcll(row[k] ^ W4p[jj * KW2 + k]);
        out[(size_t)(row0 + r) * DOUT + jj] = __fadd_rn((float)(HID - 2 * mm), b4[jj]);
    }
}

extern "C" void kernel_launch(void* const* d_in, const int* in_sizes, int n_in,
                              void* d_out, int out_size, void* d_ws, size_t ws_size,
                              hipStream_t stream)
{
    const float* x   = (const float*)d_in[0];
    const float* w1  = (const float*)d_in[1];
    const float* b1  = (const float*)d_in[2];
    const float* g1  = (const float*)d_in[3];
    const float* be1 = (const float*)d_in[4];
    const float* m1  = (const float*)d_in[5];
    const float* v1  = (const float*)d_in[6];
    const float* w2  = (const float*)d_in[7];
    const float* b2  = (const float*)d_in[8];
    const float* g2  = (const float*)d_in[9];
    const float* be2 = (const float*)d_in[10];
    const float* m2  = (const float*)d_in[11];
    const float* v2  = (const float*)d_in[12];
    const float* w3  = (const float*)d_in[13];
    const float* b3  = (const float*)d_in[14];
    const float* g3  = (const float*)d_in[15];
    const float* be3 = (const float*)d_in[16];
    const float* m3  = (const float*)d_in[17];
    const float* v3  = (const float*)d_in[18];
    const float* w4  = (const float*)d_in[19];
    const float* b4  = (const float*)d_in[20];
    float* out = (float*)d_out;

    // workspace: packed weights only (~119 KB, u64-aligned)
    u64* W1T = (u64*)d_ws;
    u64* W2T = W1T + (size_t)KW1 * HID;
    u64* W3T = W2T + (size_t)KW2 * HID;
    u64* W4p = W3T + (size_t)KW2 * HID;

    // one combined weight-pack dispatch:
    // waves = 512*13 + 512*8 + 512*8 + 10*8 = 14928 -> 3732 blocks of 256
    const int packWaves = HID * KW1 + 2 * HID * KW2 + DOUT * KW2;
    bmlp_pack_w<<<dim3((packWaves * 64 + 255) / 256), 256, 0, stream>>>(
        w1, w2, w3, w4, W1T, W2T, W3T, W4p);

    // fused pack-x + 4-layer MLP
    bmlp_fused<<<dim3(NB / RB), THR, 0, stream>>>(
        x, W1T, W2T, W3T, W4p,
        b1, g1, be1, m1, v1,
        b2, g2, be2, m2, v2,
        b3, g3, be3, m3, v3,
        b4, out);
}